// Round 2
// baseline (211.403 us; speedup 1.0000x reference)
//
#include <hip/hip_runtime.h>

// LTC cell: B=1024, I=128, N=256, 6 unfolds.
// Round 6: N-SPLIT PAIR KERNEL, regular launch (coop launch is not
// graph-capturable -> R5 never ran). Grid 512 = 2 blocks/CU (32 waves/CU).
// Each block owns 4 batches x 128 output columns -> total weight stream per
// unfold stays 1.5 GB (traffic-neutral occupancy doubling; batch-split would
// have doubled it and hit the L2 BW ceiling). Block pairs (blk^1) exchange
// their 2 KB v-half per unfold through the LLC using RELAXED agent-scope
// atomics only (no acquire/release fences -> no buffer_inv -> Prec/Psen stay
// hot in each XCD's L2). Co-residency of all 512 blocks is guaranteed by
// __launch_bounds__(1024, 8): VGPR capped at 64, LDS 38 KB -> exactly
// 2 blocks/CU, so the whole grid is resident and the pair spin cannot starve.

#define LOG2E 1.44269504088896340f

constexpr int Bn = 1024;
constexpr int In = 128;
constexpr int Nn = 256;
constexpr int UNFOLDS = 6;

#if __has_builtin(__builtin_amdgcn_exp2f)
#define EXP2F(x) __builtin_amdgcn_exp2f(x)
#else
#define EXP2F(x) __exp2f(x)
#endif
#if __has_builtin(__builtin_amdgcn_rcpf)
#define RCPF(x) __builtin_amdgcn_rcpf(x)
#else
#define RCPF(x) (1.0f / (x))
#endif

// ---------------------------------------------------------------------------
// Pack: Prec[i*N+n] = {sigma*log2e, sigma*mu*log2e, W, W*erev}; same for Psen.
// sigmoid(sigma*(v-mu)) = 1/(1 + exp2(B - A*v)), A=sigma*log2e, B=sigma*mu*log2e.
// ---------------------------------------------------------------------------
__global__ __launch_bounds__(256) void pack_kernel(
    const float* __restrict__ mu, const float* __restrict__ sigma,
    const float* __restrict__ W, const float* __restrict__ erev,
    const float* __restrict__ smu, const float* __restrict__ ssigma,
    const float* __restrict__ sW, const float* __restrict__ serev,
    float4* __restrict__ Prec, float4* __restrict__ Psen) {
    int idx = blockIdx.x * 256 + threadIdx.x;
    if (idx < Nn * Nn) {
        float s = sigma[idx], m = mu[idx], w = W[idx], e = erev[idx];
        Prec[idx] = make_float4(s * LOG2E, s * m * LOG2E, w, w * e);
        return;
    }
    int j = idx - Nn * Nn;
    if (j < In * Nn) {
        float s = ssigma[j], m = smu[j], w = sW[j], e = serev[j];
        Psen[j] = make_float4(s * LOG2E, s * m * LOG2E, w, w * e);
    }
}

// ---------------------------------------------------------------------------
// Fused LTC kernel, n-split across block pairs.
// Block blk: pair = blk>>1 (batch group b0 = pair*4), nh = blk&1 (column half).
// 1024 threads = (nl = tid&127 : local column) x (ih = tid>>7 : 8 i-slices).
// Waves 0-7 ("red" threads, ih<4) also own the per-(bb=ih, ng) state update.
// LDS: vt[256] float4 (full v, 4 batches packed) | xs[128] float4 | part 32KB.
// Exchange: xchg[parity][blk][nl*4+bb] float -> partner pull is 512
// consecutive floats straight into vt's linear half. flags[pair]: monotone
// counter, +1 per block per unfold; wait for 2*(u+1).
// ---------------------------------------------------------------------------
__global__ __launch_bounds__(1024, 8) void ltc_fused_kernel(
    const float* __restrict__ inputs, const float* __restrict__ state,
    const float* __restrict__ input_w, const float* __restrict__ input_b,
    const float4* __restrict__ Psen, const float4* __restrict__ Prec,
    const float* __restrict__ vleak, const float* __restrict__ gleak,
    const float* __restrict__ cmt, float* __restrict__ out,
    float* __restrict__ xchg, int* __restrict__ flags) {
    __shared__ float4 vt[Nn];            // [i] -> 4 batches packed, 4 KB
    __shared__ float4 xs[In];            // sensory x, [i] -> 4 batches, 2 KB
    __shared__ float2 part[8][4][128];   // [ih][bb][nl], 32 KB

    const int tid    = threadIdx.x;
    const int blk    = blockIdx.x;
    const int pairid = blk >> 1;
    const int nh     = blk & 1;
    const int b0     = pairid * 4;
    const int nl     = tid & 127;        // local column 0..127
    const int ih     = tid >> 7;         // i-slice 0..7 (wave-uniform)
    const int ng     = (nh << 7) + nl;   // global column

    // ---- fill: full v state (all 256 i, 4 batches) + sensory x ----
    {
        int i = tid & 255, bb = tid >> 8;
        ((float*)vt)[i * 4 + bb] = state[(b0 + bb) * Nn + i];   // coalesced
    }
    if (tid < 512) {
        int i = tid & 127, bb = tid >> 7;
        ((float*)xs)[i * 4 + bb] =
            inputs[(b0 + bb) * In + i] * input_w[i] + input_b[i];
    }
    const bool is_red = (ih < 4);        // wave-uniform (waves 0..7)
    float vp = 0.f, g = 0.f, c = 0.f, gvl = 0.f;
    if (is_red) {                        // this thread's (bb=ih, ng) params
        g   = gleak[ng];
        c   = cmt[ng];
        gvl = g * vleak[ng];
    }
    __syncthreads();
    if (is_red) vp = ((const float*)vt)[ng * 4 + ih];

    // ---- sensory sums (i = 0..127, slice 16 per ih) ----
    float sens_n = 0.f, sens_d = 0.f;
    {
        float num[4] = {0.f, 0.f, 0.f, 0.f};
        float den[4] = {0.f, 0.f, 0.f, 0.f};
        const float4* __restrict__ pp = Psen + ng;
#pragma unroll 8
        for (int i = ih * 16; i < ih * 16 + 16; ++i) {
            float4 p = pp[i * Nn];   // coalesced dwordx4 (64 consecutive cols)
            float4 v = xs[i];        // b128 broadcast (i wave-uniform)
#pragma unroll
            for (int bb = 0; bb < 4; ++bb) {
                float vb = (bb == 0) ? v.x : (bb == 1) ? v.y : (bb == 2) ? v.z : v.w;
                float r = RCPF(1.0f + EXP2F(fmaf(-p.x, vb, p.y)));
                den[bb] += p.z * r;
                num[bb] += p.w * r;
            }
        }
#pragma unroll
        for (int bb = 0; bb < 4; ++bb)
            part[ih][bb][nl] = make_float2(num[bb], den[bb]);
        __syncthreads();
        if (is_red) {
#pragma unroll
            for (int s = 0; s < 8; ++s) {
                float2 v = part[s][ih][nl];
                sens_n += v.x;
                sens_d += v.y;
            }
        }
    }

    // ---- 6 unfolds, pairwise v-exchange between them ----
    const float4* __restrict__ pp = Prec + ng;
    for (int u = 0; u < UNFOLDS; ++u) {
        __syncthreads();  // vt fully assembled; part reusable
        float num[4] = {0.f, 0.f, 0.f, 0.f};
        float den[4] = {0.f, 0.f, 0.f, 0.f};
#pragma unroll 8
        for (int i = ih * 32; i < ih * 32 + 32; ++i) {
            float4 p = pp[i * Nn];   // coalesced dwordx4 (L2-resident stream)
            float4 v = vt[i];        // b128 broadcast
#pragma unroll
            for (int bb = 0; bb < 4; ++bb) {
                float vb = (bb == 0) ? v.x : (bb == 1) ? v.y : (bb == 2) ? v.z : v.w;
                float r = RCPF(1.0f + EXP2F(fmaf(-p.x, vb, p.y)));
                den[bb] += p.z * r;
                num[bb] += p.w * r;
            }
        }
#pragma unroll
        for (int bb = 0; bb < 4; ++bb)
            part[ih][bb][nl] = make_float2(num[bb], den[bb]);
        __syncthreads();

        if (is_red) {  // waves 0..7: finish (bb=ih, ng)
            float wn = sens_n, wd = sens_d;
#pragma unroll
            for (int s = 0; s < 8; ++s) {
                float2 v = part[s][ih][nl];
                wn += v.x;
                wd += v.y;
            }
            float res = (c * vp + gvl + wn) * RCPF(c + g + wd);
            vp = res;
            if (u == UNFOLDS - 1) {
                out[(b0 + ih) * Nn + ng] = res;          // coalesced final store
            } else {
                ((float*)vt)[ng * 4 + ih] = res;         // own half into LDS
                // publish own half to partner in partner's vt-linear layout
                // (LLC-coherent sc-flagged store; never needs a cache fence)
                __hip_atomic_store(
                    &xchg[(((u & 1) << 9) + blk) * 512 + (nl << 2) + ih], res,
                    __ATOMIC_RELAXED, __HIP_MEMORY_SCOPE_AGENT);
            }
        }

        if (u < UNFOLDS - 1) {
            // __syncthreads() emits s_waitcnt vmcnt(0) per wave -> all payload
            // stores of this block completed at the LLC before we signal.
            __syncthreads();
            if (tid == 0) {
                __hip_atomic_fetch_add(&flags[pairid], 1, __ATOMIC_RELAXED,
                                       __HIP_MEMORY_SCOPE_AGENT);
                const int target = 2 * (u + 1);
                int it = 0;
                while (__hip_atomic_load(&flags[pairid], __ATOMIC_RELAXED,
                                         __HIP_MEMORY_SCOPE_AGENT) < target) {
                    __builtin_amdgcn_s_sleep(2);
                    if (++it > (1 << 20)) break;  // fail loud, never hang
                }
            }
            __syncthreads();
            // pull partner's half: 512 consecutive floats -> vt linear half
            if (tid < 512) {
                float pv = __hip_atomic_load(
                    &xchg[(((u & 1) << 9) + (blk ^ 1)) * 512 + tid],
                    __ATOMIC_RELAXED, __HIP_MEMORY_SCOPE_AGENT);
                ((float*)vt)[((1 - nh) << 9) + tid] = pv;
            }
            // loop-top __syncthreads makes vt writes visible to all
        }
    }
}

// ---------------------------------------------------------------------------
extern "C" void kernel_launch(void* const* d_in, const int* in_sizes, int n_in,
                              void* d_out, int out_size, void* d_ws, size_t ws_size,
                              hipStream_t stream) {
    const float* inputs   = (const float*)d_in[0];
    const float* state    = (const float*)d_in[1];
    const float* input_w  = (const float*)d_in[2];
    const float* input_b  = (const float*)d_in[3];
    const float* smu      = (const float*)d_in[4];
    const float* ssigma   = (const float*)d_in[5];
    const float* sW       = (const float*)d_in[6];
    const float* serev    = (const float*)d_in[7];
    const float* mu       = (const float*)d_in[8];
    const float* sigma    = (const float*)d_in[9];
    const float* W        = (const float*)d_in[10];
    const float* erev     = (const float*)d_in[11];
    const float* vleak    = (const float*)d_in[12];
    const float* gleak    = (const float*)d_in[13];
    const float* cmt      = (const float*)d_in[14];
    float* out = (float*)d_out;

    // Workspace: Prec 1 MiB | Psen 512 KiB | xchg 2 MiB | flags 1 KiB
    char* ws = (char*)d_ws;
    float4* Prec = (float4*)ws;
    float4* Psen = (float4*)(ws + (1u << 20));
    float*  xchg = (float*)(ws + (1u << 20) + (1u << 19));
    int*    flags = (int*)(ws + (1u << 20) + (1u << 19) + (2u << 20));

    // Pair barrier counters must start at 0 each launch (graph-capturable).
    hipMemsetAsync(flags, 0, 256 * sizeof(int), stream);

    pack_kernel<<<(Nn * Nn + In * Nn + 255) / 256, 256, 0, stream>>>(
        mu, sigma, W, erev, smu, ssigma, sW, serev, Prec, Psen);

    // Plain launch: __launch_bounds__(1024,8) caps VGPR at 64 -> exactly
    // 2 blocks/CU -> all 512 blocks co-resident; the pair spin cannot starve.
    ltc_fused_kernel<<<dim3(Bn / 4 * 2), dim3(1024), 0, stream>>>(
        inputs, state, input_w, input_b, Psen, Prec, vleak, gleak, cmt, out,
        xchg, flags);
}

// Round 3
// 180.724 us; speedup vs baseline: 1.1698x; 1.1698x over previous
//
#include <hip/hip_runtime.h>

// LTC cell: B=1024, I=128, N=256, 6 unfolds. Round 7: back to the proven
// 256-block fully-fused kernel (R0, 114 us), plus PAIRWISE-RCP: two sigmoids
// share one v_rcp_f32 via 1/(a0*a1). Cuts per-element issue from ~24 to ~19
// SIMD-cycles (trans pipe is 2/3 of issue; rcp count halves). R6 post-mortem
// showed occupancy is NOT the constraint (72% occ -> slower); issue count is.
// Each block owns 4 batches x all 256 neurons -> no cross-block deps across
// unfolds; whole 6-step recurrence in one kernel with __syncthreads.

#define LOG2E 1.44269504088896340f

constexpr int Bn = 1024;
constexpr int In = 128;
constexpr int Nn = 256;
constexpr int UNFOLDS = 6;

#if __has_builtin(__builtin_amdgcn_exp2f)
#define EXP2F(x) __builtin_amdgcn_exp2f(x)
#else
#define EXP2F(x) __exp2f(x)
#endif
#if __has_builtin(__builtin_amdgcn_rcpf)
#define RCPF(x) __builtin_amdgcn_rcpf(x)
#else
#define RCPF(x) (1.0f / (x))
#endif

// ---------------------------------------------------------------------------
// Pack: Prec[i*N+n] = {sigma*log2e, sigma*mu*log2e, W, W*erev}; same for Psen.
// sigmoid(sigma*(v-mu)) = 1/(1 + exp2(B - A*v)), A=sigma*log2e, B=sigma*mu*log2e.
// ---------------------------------------------------------------------------
__global__ __launch_bounds__(256) void pack_kernel(
    const float* __restrict__ mu, const float* __restrict__ sigma,
    const float* __restrict__ W, const float* __restrict__ erev,
    const float* __restrict__ smu, const float* __restrict__ ssigma,
    const float* __restrict__ sW, const float* __restrict__ serev,
    float4* __restrict__ Prec, float4* __restrict__ Psen) {
    int idx = blockIdx.x * 256 + threadIdx.x;
    if (idx < Nn * Nn) {
        float s = sigma[idx], m = mu[idx], w = W[idx], e = erev[idx];
        Prec[idx] = make_float4(s * LOG2E, s * m * LOG2E, w, w * e);
        return;
    }
    int j = idx - Nn * Nn;
    if (j < In * Nn) {
        float s = ssigma[j], m = smu[j], w = sW[j], e = serev[j];
        Psen[j] = make_float4(s * LOG2E, s * m * LOG2E, w, w * e);
    }
}

// ---------------------------------------------------------------------------
// Fused LTC kernel: sensory + 6 unfolds. Grid = 256 blocks x 1024 threads.
// Pairwise sigmoid: elements (bb0,bb1) and (bb2,bb3) of each i share a rcp.
//   a_k = 1 + exp2(B - A*v_k);  rp = rcp(a0*a1);  r0 = a1*rp;  r1 = a0*rp.
// Saturation-safe: product overflow -> rp=0 -> r0=r1=0 (the correct limit).
// ---------------------------------------------------------------------------
__global__ __launch_bounds__(1024, 1) void ltc_fused_kernel(
    const float* __restrict__ inputs, const float* __restrict__ state,
    const float* __restrict__ input_w, const float* __restrict__ input_b,
    const float4* __restrict__ Psen, const float4* __restrict__ Prec,
    const float* __restrict__ vleak, const float* __restrict__ gleak,
    const float* __restrict__ cmt, float* __restrict__ out) {
    __shared__ float4 vt[Nn];            // [i] -> 4 batches packed, 4 KB
    __shared__ float2 part[4][4][Nn];    // [ih][bb][n], 32 KB
    __shared__ float4 xs[In];            // sensory x, [i] -> 4 batches, 2 KB

    const int tid = threadIdx.x;
    const int b0 = blockIdx.x * 4;
    const int n = tid & 255;
    const int ih = tid >> 8;  // 0..3 : i-slice for compute, bb for reduce

    // ---- fill: v state (this thread's (bb=ih, n) value) + sensory x ----
    float vp = state[(b0 + ih) * Nn + n];      // coalesced
    ((float*)vt)[n * 4 + ih] = vp;
    if (tid < 4 * In) {
        int i = tid & 127, bb = tid >> 7;      // bb in 0..3
        ((float*)xs)[i * 4 + bb] =
            inputs[(b0 + bb) * In + i] * input_w[i] + input_b[i];
    }
    // leak params for this thread's n (wavefront-coalesced loads)
    const float g = gleak[n], c = cmt[n];
    const float gvl = g * vleak[n];
    __syncthreads();

    // ---- sensory sums (i = 0..127, slice 32 per ih) ----
    float sens_n, sens_d;
    {
        float num[4] = {0.f, 0.f, 0.f, 0.f};
        float den[4] = {0.f, 0.f, 0.f, 0.f};
        const float4* __restrict__ pp = Psen + n;
#pragma unroll 8
        for (int i = ih * 32; i < ih * 32 + 32; ++i) {
            float4 p = pp[i * Nn];   // coalesced dwordx4
            float4 v = xs[i];        // b128 broadcast (ih wave-uniform)
            float a0 = 1.0f + EXP2F(fmaf(-p.x, v.x, p.y));
            float a1 = 1.0f + EXP2F(fmaf(-p.x, v.y, p.y));
            float a2 = 1.0f + EXP2F(fmaf(-p.x, v.z, p.y));
            float a3 = 1.0f + EXP2F(fmaf(-p.x, v.w, p.y));
            float rp01 = RCPF(a0 * a1);
            float rp23 = RCPF(a2 * a3);
            float r0 = a1 * rp01, r1 = a0 * rp01;
            float r2 = a3 * rp23, r3 = a2 * rp23;
            den[0] += p.z * r0; num[0] += p.w * r0;
            den[1] += p.z * r1; num[1] += p.w * r1;
            den[2] += p.z * r2; num[2] += p.w * r2;
            den[3] += p.z * r3; num[3] += p.w * r3;
        }
#pragma unroll
        for (int bb = 0; bb < 4; ++bb)
            part[ih][bb][n] = make_float2(num[bb], den[bb]);
        __syncthreads();
        float wn = 0.f, wd = 0.f;
#pragma unroll
        for (int s = 0; s < 4; ++s) {
            float2 v = part[s][ih][n];  // this thread's bb == ih
            wn += v.x;
            wd += v.y;
        }
        sens_n = wn;
        sens_d = wd;
    }

    // ---- 6 unfolds ----
    const float4* __restrict__ pp = Prec + n;
    for (int s = 0; s < UNFOLDS; ++s) {
        __syncthreads();  // vt writes from prev step visible; part reusable
        float num[4] = {0.f, 0.f, 0.f, 0.f};
        float den[4] = {0.f, 0.f, 0.f, 0.f};
#pragma unroll 8
        for (int i = ih * 64; i < ih * 64 + 64; ++i) {
            float4 p = pp[i * Nn];   // coalesced dwordx4 (L2-resident stream)
            float4 v = vt[i];        // b128 broadcast
            float a0 = 1.0f + EXP2F(fmaf(-p.x, v.x, p.y));
            float a1 = 1.0f + EXP2F(fmaf(-p.x, v.y, p.y));
            float a2 = 1.0f + EXP2F(fmaf(-p.x, v.z, p.y));
            float a3 = 1.0f + EXP2F(fmaf(-p.x, v.w, p.y));
            float rp01 = RCPF(a0 * a1);
            float rp23 = RCPF(a2 * a3);
            float r0 = a1 * rp01, r1 = a0 * rp01;
            float r2 = a3 * rp23, r3 = a2 * rp23;
            den[0] += p.z * r0; num[0] += p.w * r0;
            den[1] += p.z * r1; num[1] += p.w * r1;
            den[2] += p.z * r2; num[2] += p.w * r2;
            den[3] += p.z * r3; num[3] += p.w * r3;
        }
#pragma unroll
        for (int bb = 0; bb < 4; ++bb)
            part[ih][bb][n] = make_float2(num[bb], den[bb]);
        __syncthreads();
        // reduce for this thread's (bb=ih, n)
        float wn = sens_n, wd = sens_d;
#pragma unroll
        for (int s2 = 0; s2 < 4; ++s2) {
            float2 v = part[s2][ih][n];
            wn += v.x;
            wd += v.y;
        }
        float res = (c * vp + gvl + wn) * RCPF(c + g + wd);
        vp = res;
        if (s == UNFOLDS - 1)
            out[(b0 + ih) * Nn + n] = res;       // coalesced final store
        else
            ((float*)vt)[n * 4 + ih] = res;
    }
}

// ---------------------------------------------------------------------------
extern "C" void kernel_launch(void* const* d_in, const int* in_sizes, int n_in,
                              void* d_out, int out_size, void* d_ws, size_t ws_size,
                              hipStream_t stream) {
    const float* inputs   = (const float*)d_in[0];
    const float* state    = (const float*)d_in[1];
    const float* input_w  = (const float*)d_in[2];
    const float* input_b  = (const float*)d_in[3];
    const float* smu      = (const float*)d_in[4];
    const float* ssigma   = (const float*)d_in[5];
    const float* sW       = (const float*)d_in[6];
    const float* serev    = (const float*)d_in[7];
    const float* mu       = (const float*)d_in[8];
    const float* sigma    = (const float*)d_in[9];
    const float* W        = (const float*)d_in[10];
    const float* erev     = (const float*)d_in[11];
    const float* vleak    = (const float*)d_in[12];
    const float* gleak    = (const float*)d_in[13];
    const float* cmt      = (const float*)d_in[14];
    float* out = (float*)d_out;

    // Workspace: Prec 1 MiB | Psen 512 KiB
    char* ws = (char*)d_ws;
    float4* Prec = (float4*)ws;
    float4* Psen = (float4*)(ws + (1u << 20));

    pack_kernel<<<(Nn * Nn + In * Nn + 255) / 256, 256, 0, stream>>>(
        mu, sigma, W, erev, smu, ssigma, sW, serev, Prec, Psen);

    ltc_fused_kernel<<<Bn / 4, 1024, 0, stream>>>(
        inputs, state, input_w, input_b, Psen, Prec, vleak, gleak, cmt, out);
}